// Round 2
// baseline (146.684 us; speedup 1.0000x reference)
//
#include <hip/hip_runtime.h>

typedef __attribute__((ext_vector_type(8))) short short8;
typedef __attribute__((ext_vector_type(4))) float float4v;

// win(i) bitmasks: bit hr set if hr in window of i (H=16, PART=4 -> 4-row clamped windows)
__constant__ unsigned short WIN[16] = {
    0x000F, 0x000F, 0x000F, 0x001E, 0x003C, 0x0078, 0x00F0, 0x01E0,
    0x03C0, 0x0780, 0x0F00, 0x1E00, 0x3C00, 0x7800, 0xF000, 0xF000
};

__device__ __forceinline__ unsigned short f2bf(float f) {
    unsigned int x = __builtin_bit_cast(unsigned int, f);
    x += 0x7FFF + ((x >> 16) & 1);   // round-to-nearest-even
    return (unsigned short)(x >> 16);
}

struct __align__(16) U16x8 { unsigned short u[8]; };

// Kernel A: one block per (probe, gallery) pair. Inputs are FLOAT32 [48][64][256];
// staged to LDS as bf16 (RTNE) with an 8x8 register transpose + XOR chunk swizzle.
// Computes banded score tiles with MFMA, windowed maxes s1/s2, reduces to 3 scalars:
// dot((s1+s2), fc_w), sum(s1)+sum(s2), sum(s1^2)+sum(s2^2).
__global__ __launch_bounds__(256) void score_pam_kernel(
    const float* __restrict__ prob,   // [48][64][256] f32
    const float* __restrict__ gal,    // [48][64][256] f32
    const float* __restrict__ fcw,    // [256] f32
    float* __restrict__ outDot,       // [2304]
    float* __restrict__ outSum,       // [2304]
    float* __restrict__ outSq)        // [2304]
{
    __shared__ unsigned short pfT[256 * 64];   // [s][c] bf16, chunk-swizzled, 32 KB
    __shared__ unsigned short gfT[128 * 64];   // [r-local][c] bf16, swizzled, 16 KB
    __shared__ float s1part[4 * 256];          // per-wave s1 partial maxes
    __shared__ float s2buf[256];
    __shared__ float red[12];

    const int tid = threadIdx.x;
    const int pair = blockIdx.x;
    const int ip = pair / 48;
    const int ig = pair % 48;
    const float* pbase = prob + ip * 16384;
    const float* gbase = gal + ig * 16384;

    for (int i = tid; i < 1024; i += 256) s1part[i] = -3.0e38f;

    // ---- stage pfT: read [c][s] f32 (8x8 block per thread), cvt bf16, register
    // transpose, write [s][c] with chunk' = (c/8) ^ (s%8) swizzle (conflict-free).
    {
        const int c0 = (tid & 7) * 8;
        const int s0 = (tid >> 3) * 8;
        unsigned short in[8][8];
#pragma unroll
        for (int i = 0; i < 8; ++i) {
            const float* src = pbase + (c0 + i) * 256 + s0;
            const float4v f0 = *(const float4v*)(src);
            const float4v f1 = *(const float4v*)(src + 4);
            in[i][0] = f2bf(f0.x); in[i][1] = f2bf(f0.y);
            in[i][2] = f2bf(f0.z); in[i][3] = f2bf(f0.w);
            in[i][4] = f2bf(f1.x); in[i][5] = f2bf(f1.y);
            in[i][6] = f2bf(f1.z); in[i][7] = f2bf(f1.w);
        }
#pragma unroll
        for (int j = 0; j < 8; ++j) {
            U16x8 o;
#pragma unroll
            for (int i = 0; i < 8; ++i) o.u[i] = in[i][j];
            const int srow = s0 + j;
            const int off = srow * 64 + (((c0 >> 3) ^ (srow & 7)) << 3);
            *(U16x8*)(pfT + off) = o;
        }
    }

    const int lane = tid & 63;
    const int w = tid >> 6;
    const int laneM = lane & 15;
    const int q = lane >> 4;
    const int swzl = laneM & 7;

    for (int phase = 0; phase < 2; ++phase) {
        __syncthreads();   // pfT ready (phase 0) / previous phase readers done
        if (tid < 128) {   // stage gfT rows [128*phase, 128*phase+128)
            const int c0 = (tid & 7) * 8;
            const int r0l = (tid >> 3) * 8;
            unsigned short in[8][8];
#pragma unroll
            for (int i = 0; i < 8; ++i) {
                const float* src = gbase + (c0 + i) * 256 + r0l + phase * 128;
                const float4v f0 = *(const float4v*)(src);
                const float4v f1 = *(const float4v*)(src + 4);
                in[i][0] = f2bf(f0.x); in[i][1] = f2bf(f0.y);
                in[i][2] = f2bf(f0.z); in[i][3] = f2bf(f0.w);
                in[i][4] = f2bf(f1.x); in[i][5] = f2bf(f1.y);
                in[i][6] = f2bf(f1.z); in[i][7] = f2bf(f1.w);
            }
#pragma unroll
            for (int j = 0; j < 8; ++j) {
                U16x8 o;
#pragma unroll
                for (int i = 0; i < 8; ++i) o.u[i] = in[i][j];
                const int rrow = r0l + j;
                const int off = rrow * 64 + (((c0 >> 3) ^ (rrow & 7)) << 3);
                *(U16x8*)(gfT + off) = o;
            }
        }
        __syncthreads();

#pragma unroll
        for (int hh = 0; hh < 2; ++hh) {
            const int hr = phase * 8 + w * 2 + hh;        // wave-exclusive hr
            const unsigned int winHr = WIN[hr];
            float4v s2run = { -3.0e38f, -3.0e38f, -3.0e38f, -3.0e38f };
            const int rl = (hr - phase * 8) * 16 + laneM; // gfT local row (A: m=laneM)

            for (int hc = 0; hc < 16; ++hc) {
                const bool inS1 = (WIN[hc] >> hr) & 1;    // hr in win(hc)
                const bool inS2 = (winHr >> hc) & 1;      // hc in win(hr)
                if (!(inS1 || inS2)) continue;            // banded skip (78/256 tiles)

                const int sl = hc * 16 + laneM;
                const short8 a0 = *(const short8*)(gfT + rl * 64 + ((q ^ swzl) << 3));
                const short8 a1 = *(const short8*)(gfT + rl * 64 + (((q + 4) ^ swzl) << 3));
                const short8 b0 = *(const short8*)(pfT + sl * 64 + ((q ^ swzl) << 3));
                const short8 b1 = *(const short8*)(pfT + sl * 64 + (((q + 4) ^ swzl) << 3));
                float4v acc = { 0.f, 0.f, 0.f, 0.f };
                acc = __builtin_amdgcn_mfma_f32_16x16x32_bf16(a0, b0, acc, 0, 0, 0);
                acc = __builtin_amdgcn_mfma_f32_16x16x32_bf16(a1, b1, acc, 0, 0, 0);
                // acc.i = score(r = hr*16 + q*4+i, s = hc*16 + laneM)

                if (inS2) {  // s2: max over (hc in win(hr), all wc) per row r
                    s2run.x = fmaxf(s2run.x, acc.x);
                    s2run.y = fmaxf(s2run.y, acc.y);
                    s2run.z = fmaxf(s2run.z, acc.z);
                    s2run.w = fmaxf(s2run.w, acc.w);
                }
                if (inS1) {  // s1: col-max over all wr, then max over hr in win(hc)
                    float cm = fmaxf(fmaxf(acc.x, acc.y), fmaxf(acc.z, acc.w));
                    cm = fmaxf(cm, __shfl_xor(cm, 16, 64));
                    cm = fmaxf(cm, __shfl_xor(cm, 32, 64));
                    if (lane < 16) {   // one lane per col; wave-private slice
                        float* p = &s1part[w * 256 + hc * 16 + lane];
                        *p = fmaxf(*p, cm);
                    }
                }
            }
            // finish s2 rows for this hr: max across the 16 cols (lanes of quad)
#pragma unroll
            for (int d = 1; d < 16; d <<= 1) {
                s2run.x = fmaxf(s2run.x, __shfl_xor(s2run.x, d, 64));
                s2run.y = fmaxf(s2run.y, __shfl_xor(s2run.y, d, 64));
                s2run.z = fmaxf(s2run.z, __shfl_xor(s2run.z, d, 64));
                s2run.w = fmaxf(s2run.w, __shfl_xor(s2run.w, d, 64));
            }
            if (laneM == 0) {
                const int r0 = hr * 16 + q * 4;
                s2buf[r0 + 0] = s2run.x;
                s2buf[r0 + 1] = s2run.y;
                s2buf[r0 + 2] = s2run.z;
                s2buf[r0 + 3] = s2run.w;
            }
        }
    }
    __syncthreads();

    // ---- per-pair reduction to 3 scalars (linear downstream => sufficient stats)
    {
        const float s1v = fmaxf(fmaxf(s1part[tid], s1part[256 + tid]),
                                fmaxf(s1part[512 + tid], s1part[768 + tid]));
        const float s2v = s2buf[tid];
        const float wj = fcw[tid];
        float dv = (s1v + s2v) * wj;
        float sv = s1v + s2v;
        float qv = s1v * s1v + s2v * s2v;
#pragma unroll
        for (int d = 32; d >= 1; d >>= 1) {
            dv += __shfl_down(dv, d, 64);
            sv += __shfl_down(sv, d, 64);
            qv += __shfl_down(qv, d, 64);
        }
        if (lane == 0) { red[w] = dv; red[4 + w] = sv; red[8 + w] = qv; }
        __syncthreads();
        if (tid == 0) {
            outDot[pair] = red[0] + red[1] + red[2] + red[3];
            outSum[pair] = red[4] + red[5] + red[6] + red[7];
            outSq[pair] = red[8] + red[9] + red[10] + red[11];
        }
    }
}

// Kernel B: single block. Global BN1 stats over all 1,179,648 sc values (from
// per-pair sums), fc (linear), pair-sum, BN2 over 2304, sigmoid, f32 store.
__global__ __launch_bounds__(256) void finalize_kernel(
    const float* __restrict__ dDot,
    const float* __restrict__ dSum,
    const float* __restrict__ dSq,
    const float* __restrict__ bng,
    const float* __restrict__ bnb,
    const float* __restrict__ fcw,
    const float* __restrict__ fcb,
    const float* __restrict__ lg,
    const float* __restrict__ lb,
    float* __restrict__ outp)   // [2304] f32
{
    __shared__ float red[12];
    const int tid = threadIdx.x;
    const int lane = tid & 63;
    const int w = tid >> 6;

    float S = 0.f, Q = 0.f;
    float dv[9];
#pragma unroll
    for (int k = 0; k < 9; ++k) {
        const int i = tid + 256 * k;
        dv[k] = dDot[i];
        S += dSum[i];
        Q += dSq[i];
    }
    float Wj = fcw[tid];
#pragma unroll
    for (int d = 32; d >= 1; d >>= 1) {
        S += __shfl_down(S, d, 64);
        Q += __shfl_down(Q, d, 64);
        Wj += __shfl_down(Wj, d, 64);
    }
    if (lane == 0) { red[w] = S; red[4 + w] = Q; red[8 + w] = Wj; }
    __syncthreads();
    S = red[0] + red[1] + red[2] + red[3];
    Q = red[4] + red[5] + red[6] + red[7];
    const float W = red[8] + red[9] + red[10] + red[11];
    __syncthreads();

    const float N1 = 1179648.0f;           // 4608 * 256 elements in BN1
    const float m1 = S / N1;
    const float v1 = Q / N1 - m1 * m1;     // biased var (torch training default)
    const float inv1 = rsqrtf(v1 + 1e-5f);
    const float g1 = bng[0], b1 = bnb[0], fb = fcb[0];
    const float g2 = lg[0], b2 = lb[0];
    // y_pair = g1*inv1*(dot - 2*m1*W) + 2*(b1*W + fb)   (fc is linear after BN)
    const float cA = g1 * inv1;
    const float cB = 2.f * (b1 * W + fb) - cA * 2.f * m1 * W;

    float Sy = 0.f, Qy = 0.f;
    float yv[9];
#pragma unroll
    for (int k = 0; k < 9; ++k) {
        const float y = cA * dv[k] + cB;
        yv[k] = y;
        Sy += y;
        Qy += y * y;
    }
#pragma unroll
    for (int d = 32; d >= 1; d >>= 1) {
        Sy += __shfl_down(Sy, d, 64);
        Qy += __shfl_down(Qy, d, 64);
    }
    if (lane == 0) { red[w] = Sy; red[4 + w] = Qy; }
    __syncthreads();
    Sy = red[0] + red[1] + red[2] + red[3];
    Qy = red[4] + red[5] + red[6] + red[7];

    const float m2 = Sy / 2304.0f;
    const float v2 = Qy / 2304.0f - m2 * m2;
    const float inv2 = rsqrtf(v2 + 1e-5f);
#pragma unroll
    for (int k = 0; k < 9; ++k) {
        const int i = tid + 256 * k;
        const float z = g2 * (yv[k] - m2) * inv2 + b2;
        outp[i] = 1.0f / (1.0f + __expf(-z));
    }
}

extern "C" void kernel_launch(void* const* d_in, const int* in_sizes, int n_in,
                              void* d_out, int out_size, void* d_ws, size_t ws_size,
                              hipStream_t stream) {
    const float* prob = (const float*)d_in[0];
    const float* gal  = (const float*)d_in[1];
    const float* bng  = (const float*)d_in[2];
    const float* bnb  = (const float*)d_in[3];
    const float* fcw  = (const float*)d_in[4];
    const float* fcb  = (const float*)d_in[5];
    const float* lg   = (const float*)d_in[6];
    const float* lb   = (const float*)d_in[7];

    float* ws = (float*)d_ws;
    float* dDot = ws;            // [2304]
    float* dSum = ws + 2304;     // [2304]
    float* dSq  = ws + 4608;     // [2304]

    hipLaunchKernelGGL(score_pam_kernel, dim3(48 * 48), dim3(256), 0, stream,
                       prob, gal, fcw, dDot, dSum, dSq);
    hipLaunchKernelGGL(finalize_kernel, dim3(1), dim3(256), 0, stream,
                       dDot, dSum, dSq, bng, bnb, fcw, fcb, lg, lb,
                       (float*)d_out);
}

// Round 3
// 111.043 us; speedup vs baseline: 1.3210x; 1.3210x over previous
//
#include <hip/hip_runtime.h>

typedef __attribute__((ext_vector_type(8))) short short8;
typedef __attribute__((ext_vector_type(4))) float float4v;

// win(i) bitmasks: bit hr set if hr in window of i (H=16, PART=4 -> 4-row clamped windows)
__constant__ unsigned short WIN[16] = {
    0x000F, 0x000F, 0x000F, 0x001E, 0x003C, 0x0078, 0x00F0, 0x01E0,
    0x03C0, 0x0780, 0x0F00, 0x1E00, 0x3C00, 0x7800, 0xF000, 0xF000
};
// For wave-pair t (hr = 2t, 2t+1): contiguous union of hc tiles needed for s1|s2.
__constant__ int LO8[8] = {0, 0, 2, 4, 6, 8, 10, 12};
__constant__ int HI8[8] = {3, 5, 7, 9, 11, 13, 15, 15};

__device__ __forceinline__ unsigned short f2bf(float f) {
    unsigned int x = __builtin_bit_cast(unsigned int, f);
    x += 0x7FFF + ((x >> 16) & 1);   // round-to-nearest-even
    return (unsigned short)(x >> 16);
}

struct __align__(16) U16x8 { unsigned short u[8]; };

// Kernel 0: f32 [img][64c][256s] -> bf16 [img][s][c] with chunk XOR swizzle
// (chunk' = (c/8) ^ (s%8)), exactly the LDS layout kernel A wants. imgs 0..47
// = probe, 48..95 = gallery. Runs once; kernel A staging becomes a linear copy.
__global__ __launch_bounds__(256) void pretranspose_kernel(
    const float* __restrict__ prob,
    const float* __restrict__ gal,
    unsigned short* __restrict__ outT)   // [96][16384] bf16
{
    const int img = blockIdx.x;
    const float* src = (img < 48) ? (prob + img * 16384)
                                  : (gal + (img - 48) * 16384);
    unsigned short* dst = outT + img * 16384;
    const int tid = threadIdx.x;
    const int c0 = (tid & 7) * 8;
    const int s0 = (tid >> 3) * 8;
    unsigned short v[8][8];
#pragma unroll
    for (int i = 0; i < 8; ++i) {
        const float* p = src + (c0 + i) * 256 + s0;
        const float4v f0 = *(const float4v*)(p);
        const float4v f1 = *(const float4v*)(p + 4);
        v[i][0] = f2bf(f0.x); v[i][1] = f2bf(f0.y);
        v[i][2] = f2bf(f0.z); v[i][3] = f2bf(f0.w);
        v[i][4] = f2bf(f1.x); v[i][5] = f2bf(f1.y);
        v[i][6] = f2bf(f1.z); v[i][7] = f2bf(f1.w);
    }
#pragma unroll
    for (int j = 0; j < 8; ++j) {
        U16x8 o;
#pragma unroll
        for (int i = 0; i < 8; ++i) o.u[i] = v[i][j];
        const int srow = s0 + j;
        const int off = srow * 64 + (((c0 >> 3) ^ (srow & 7)) << 3);
        *(U16x8*)(dst + off) = o;
    }
}

// Kernel A: one block per (probe, gallery) pair. LDS = 54272 B -> 3 blocks/CU.
__global__ __launch_bounds__(256, 3) void score_pam_kernel(
    const unsigned short* __restrict__ preT,  // [96][16384] bf16 pre-transposed
    const float* __restrict__ fcw,            // [256] f32
    float* __restrict__ outDot,               // [2304]
    float* __restrict__ outSum,               // [2304]
    float* __restrict__ outSq)                // [2304]
{
    __shared__ unsigned short pfT[256 * 64];   // 32 KB
    __shared__ unsigned short gfT[128 * 64];   // 16 KB (per phase: 8 hr rows)
    __shared__ float s1part[4 * 256];          // 4 KB per-wave s1 partials
    __shared__ float s2buf[256];               // 1 KB (also reused for final reduce)

    const int tid = threadIdx.x;
    const int pair = blockIdx.x;
    const int ip = pair / 48;
    const int ig = pair % 48;
    const unsigned short* pimg = preT + ip * 16384;
    const unsigned short* gimg = preT + (48 + ig) * 16384;

    {   // init s1part: 256 threads x 16 B
        float4v m = { -3.0e38f, -3.0e38f, -3.0e38f, -3.0e38f };
        *(float4v*)(s1part + tid * 4) = m;
    }
    // stage pfT: linear coalesced copy, 32 KB
#pragma unroll
    for (int j = 0; j < 8; ++j) {
        const int off = j * 2048 + tid * 8;
        *(U16x8*)(pfT + off) = *(const U16x8*)(pimg + off);
    }

    const int lane = tid & 63;
    const int w = tid >> 6;
    const int laneM = lane & 15;
    const int q = lane >> 4;
    const int swzl = laneM & 7;

    for (int phase = 0; phase < 2; ++phase) {
        if (phase) __syncthreads();   // phase-0 compute done before gfT overwrite
        // stage gfT rows [128*phase, 128*phase+128): linear copy, 16 KB
#pragma unroll
        for (int j = 0; j < 4; ++j) {
            const int off = j * 2048 + tid * 8;
            *(U16x8*)(gfT + off) = *(const U16x8*)(gimg + phase * 8192 + off);
        }
        __syncthreads();

        const int t = phase * 4 + w;
        const int hr0 = 2 * t;
        const int hr1 = hr0 + 1;
        const int rl0 = 32 * w + laneM;       // gfT local row for hr0
        const int rl1 = rl0 + 16;
        // A-fragments (gallery), hoisted across the whole hc loop
        const short8 a00 = *(const short8*)(gfT + rl0 * 64 + ((q ^ swzl) << 3));
        const short8 a01 = *(const short8*)(gfT + rl0 * 64 + (((q + 4) ^ swzl) << 3));
        const short8 a10 = *(const short8*)(gfT + rl1 * 64 + ((q ^ swzl) << 3));
        const short8 a11 = *(const short8*)(gfT + rl1 * 64 + (((q + 4) ^ swzl) << 3));
        const unsigned int win0 = WIN[hr0];
        const unsigned int win1 = WIN[hr1];
        float4v s2r0 = { -3.0e38f, -3.0e38f, -3.0e38f, -3.0e38f };
        float4v s2r1 = s2r0;
        const int lo = LO8[t], hi = HI8[t];

        int sl = lo * 16 + laneM;
        short8 b0 = *(const short8*)(pfT + sl * 64 + ((q ^ swzl) << 3));
        short8 b1 = *(const short8*)(pfT + sl * 64 + (((q + 4) ^ swzl) << 3));
        for (int hc = lo; hc <= hi; ++hc) {
            // prefetch next B-frags (clamped; redundant last iter)
            const int hcn = (hc < hi) ? hc + 1 : hc;
            const int sln = hcn * 16 + laneM;
            const short8 nb0 = *(const short8*)(pfT + sln * 64 + ((q ^ swzl) << 3));
            const short8 nb1 = *(const short8*)(pfT + sln * 64 + (((q + 4) ^ swzl) << 3));

            float4v acc0 = { 0.f, 0.f, 0.f, 0.f };
            float4v acc1 = acc0;
            acc0 = __builtin_amdgcn_mfma_f32_16x16x32_bf16(a00, b0, acc0, 0, 0, 0);
            acc0 = __builtin_amdgcn_mfma_f32_16x16x32_bf16(a01, b1, acc0, 0, 0, 0);
            acc1 = __builtin_amdgcn_mfma_f32_16x16x32_bf16(a10, b0, acc1, 0, 0, 0);
            acc1 = __builtin_amdgcn_mfma_f32_16x16x32_bf16(a11, b1, acc1, 0, 0, 0);
            // acc0.i = score(r = hr0*16 + q*4+i, s = hc*16 + laneM); acc1 -> hr1

            const bool s20 = (win0 >> hc) & 1;
            const bool s21 = (win1 >> hc) & 1;
            const unsigned int wc = WIN[hc];
            const bool s10 = (wc >> hr0) & 1;
            const bool s11 = (wc >> hr1) & 1;

            if (s20) {
                s2r0.x = fmaxf(s2r0.x, acc0.x); s2r0.y = fmaxf(s2r0.y, acc0.y);
                s2r0.z = fmaxf(s2r0.z, acc0.z); s2r0.w = fmaxf(s2r0.w, acc0.w);
            }
            if (s21) {
                s2r1.x = fmaxf(s2r1.x, acc1.x); s2r1.y = fmaxf(s2r1.y, acc1.y);
                s2r1.z = fmaxf(s2r1.z, acc1.z); s2r1.w = fmaxf(s2r1.w, acc1.w);
            }
            if (s10 || s11) {   // merged s1 update: one shfl-pair per hc
                float vm = -3.0e38f;
                if (s10) vm = fmaxf(fmaxf(acc0.x, acc0.y), fmaxf(acc0.z, acc0.w));
                if (s11) vm = fmaxf(vm, fmaxf(fmaxf(acc1.x, acc1.y),
                                              fmaxf(acc1.z, acc1.w)));
                vm = fmaxf(vm, __shfl_xor(vm, 16, 64));
                vm = fmaxf(vm, __shfl_xor(vm, 32, 64));
                if (lane < 16) {
                    float* p = &s1part[w * 256 + hc * 16 + lane];
                    *p = fmaxf(*p, vm);
                }
            }
            b0 = nb0; b1 = nb1;
        }
        // finish s2 rows: max across the 16 cols (laneM) per component
#pragma unroll
        for (int d = 1; d < 16; d <<= 1) {
            s2r0.x = fmaxf(s2r0.x, __shfl_xor(s2r0.x, d, 64));
            s2r0.y = fmaxf(s2r0.y, __shfl_xor(s2r0.y, d, 64));
            s2r0.z = fmaxf(s2r0.z, __shfl_xor(s2r0.z, d, 64));
            s2r0.w = fmaxf(s2r0.w, __shfl_xor(s2r0.w, d, 64));
            s2r1.x = fmaxf(s2r1.x, __shfl_xor(s2r1.x, d, 64));
            s2r1.y = fmaxf(s2r1.y, __shfl_xor(s2r1.y, d, 64));
            s2r1.z = fmaxf(s2r1.z, __shfl_xor(s2r1.z, d, 64));
            s2r1.w = fmaxf(s2r1.w, __shfl_xor(s2r1.w, d, 64));
        }
        if (laneM == 0) {
            const int r0 = hr0 * 16 + q * 4;
            s2buf[r0 + 0] = s2r0.x; s2buf[r0 + 1] = s2r0.y;
            s2buf[r0 + 2] = s2r0.z; s2buf[r0 + 3] = s2r0.w;
            const int r1 = hr1 * 16 + q * 4;
            s2buf[r1 + 0] = s2r1.x; s2buf[r1 + 1] = s2r1.y;
            s2buf[r1 + 2] = s2r1.z; s2buf[r1 + 3] = s2r1.w;
        }
    }
    __syncthreads();

    // ---- per-pair reduction to 3 scalars (downstream BN/fc are linear in these)
    {
        const float s1v = fmaxf(fmaxf(s1part[tid], s1part[256 + tid]),
                                fmaxf(s1part[512 + tid], s1part[768 + tid]));
        const float s2v = s2buf[tid];
        const float wj = fcw[tid];
        float dv = (s1v + s2v) * wj;
        float sv = s1v + s2v;
        float qv = s1v * s1v + s2v * s2v;
#pragma unroll
        for (int d = 32; d >= 1; d >>= 1) {
            dv += __shfl_down(dv, d, 64);
            sv += __shfl_down(sv, d, 64);
            qv += __shfl_down(qv, d, 64);
        }
        __syncthreads();               // all s2buf reads done; reuse it as scratch
        if (lane == 0) {
            s2buf[w] = dv; s2buf[8 + w] = sv; s2buf[16 + w] = qv;
        }
        __syncthreads();
        if (tid == 0) {
            outDot[pair] = s2buf[0] + s2buf[1] + s2buf[2] + s2buf[3];
            outSum[pair] = s2buf[8] + s2buf[9] + s2buf[10] + s2buf[11];
            outSq[pair]  = s2buf[16] + s2buf[17] + s2buf[18] + s2buf[19];
        }
    }
}

// Kernel B: single block. Global BN1 stats from per-pair sums, fc (linear),
// pair-sum, BN2 over 2304, sigmoid, f32 store.
__global__ __launch_bounds__(256) void finalize_kernel(
    const float* __restrict__ dDot,
    const float* __restrict__ dSum,
    const float* __restrict__ dSq,
    const float* __restrict__ bng,
    const float* __restrict__ bnb,
    const float* __restrict__ fcw,
    const float* __restrict__ fcb,
    const float* __restrict__ lg,
    const float* __restrict__ lb,
    float* __restrict__ outp)   // [2304] f32
{
    __shared__ float red[12];
    const int tid = threadIdx.x;
    const int lane = tid & 63;
    const int w = tid >> 6;

    float S = 0.f, Q = 0.f;
    float dv[9];
#pragma unroll
    for (int k = 0; k < 9; ++k) {
        const int i = tid + 256 * k;
        dv[k] = dDot[i];
        S += dSum[i];
        Q += dSq[i];
    }
    float Wj = fcw[tid];
#pragma unroll
    for (int d = 32; d >= 1; d >>= 1) {
        S += __shfl_down(S, d, 64);
        Q += __shfl_down(Q, d, 64);
        Wj += __shfl_down(Wj, d, 64);
    }
    if (lane == 0) { red[w] = S; red[4 + w] = Q; red[8 + w] = Wj; }
    __syncthreads();
    S = red[0] + red[1] + red[2] + red[3];
    Q = red[4] + red[5] + red[6] + red[7];
    const float W = red[8] + red[9] + red[10] + red[11];
    __syncthreads();

    const float N1 = 1179648.0f;           // 4608 * 256 elements in BN1
    const float m1 = S / N1;
    const float v1 = Q / N1 - m1 * m1;     // biased var (torch training default)
    const float inv1 = rsqrtf(v1 + 1e-5f);
    const float g1 = bng[0], b1 = bnb[0], fb = fcb[0];
    const float g2 = lg[0], b2 = lb[0];
    const float cA = g1 * inv1;
    const float cB = 2.f * (b1 * W + fb) - cA * 2.f * m1 * W;

    float Sy = 0.f, Qy = 0.f;
    float yv[9];
#pragma unroll
    for (int k = 0; k < 9; ++k) {
        const float y = cA * dv[k] + cB;
        yv[k] = y;
        Sy += y;
        Qy += y * y;
    }
#pragma unroll
    for (int d = 32; d >= 1; d >>= 1) {
        Sy += __shfl_down(Sy, d, 64);
        Qy += __shfl_down(Qy, d, 64);
    }
    if (lane == 0) { red[w] = Sy; red[4 + w] = Qy; }
    __syncthreads();
    Sy = red[0] + red[1] + red[2] + red[3];
    Qy = red[4] + red[5] + red[6] + red[7];

    const float m2 = Sy / 2304.0f;
    const float v2 = Qy / 2304.0f - m2 * m2;
    const float inv2 = rsqrtf(v2 + 1e-5f);
#pragma unroll
    for (int k = 0; k < 9; ++k) {
        const int i = tid + 256 * k;
        const float z = g2 * (yv[k] - m2) * inv2 + b2;
        outp[i] = 1.0f / (1.0f + __expf(-z));
    }
}

extern "C" void kernel_launch(void* const* d_in, const int* in_sizes, int n_in,
                              void* d_out, int out_size, void* d_ws, size_t ws_size,
                              hipStream_t stream) {
    const float* prob = (const float*)d_in[0];
    const float* gal  = (const float*)d_in[1];
    const float* bng  = (const float*)d_in[2];
    const float* bnb  = (const float*)d_in[3];
    const float* fcw  = (const float*)d_in[4];
    const float* fcb  = (const float*)d_in[5];
    const float* lg   = (const float*)d_in[6];
    const float* lb   = (const float*)d_in[7];

    unsigned short* preT = (unsigned short*)d_ws;        // 96*16384 bf16 = 3 MB
    float* ws = (float*)((char*)d_ws + 96 * 16384 * sizeof(unsigned short));
    float* dDot = ws;            // [2304]
    float* dSum = ws + 2304;     // [2304]
    float* dSq  = ws + 4608;     // [2304]

    hipLaunchKernelGGL(pretranspose_kernel, dim3(96), dim3(256), 0, stream,
                       prob, gal, preT);
    hipLaunchKernelGGL(score_pam_kernel, dim3(48 * 48), dim3(256), 0, stream,
                       preT, fcw, dDot, dSum, dSq);
    hipLaunchKernelGGL(finalize_kernel, dim3(1), dim3(256), 0, stream,
                       dDot, dSum, dSq, bng, bnb, fcw, fcb, lg, lb,
                       (float*)d_out);
}

// Round 6
// 102.599 us; speedup vs baseline: 1.4297x; 1.0823x over previous
//
#include <hip/hip_runtime.h>

typedef __attribute__((ext_vector_type(8))) short short8;
typedef __attribute__((ext_vector_type(4))) float float4v;

// Window tile range for kept-block i: win(i) = clamped 4-row window (H=16, PART=4).
// BOTH passes use this table: s2 keeps row-block hr, reduces hc in win(hr);
// s1 keeps col-block hc, reduces hr in win(hc). In each pass's (transposed) view
// the reduced tile range is win(kept block) = [LOW, HIW].
__constant__ int LOW[16] = {0,0,0,1,2,3,4,5,6,7,8,9,10,11,12,12};
__constant__ int HIW[16] = {3,3,3,4,5,6,7,8,9,10,11,12,13,14,15,15};

__device__ __forceinline__ unsigned short f2bf(float f) {
    unsigned int x = __builtin_bit_cast(unsigned int, f);
    x += 0x7FFF + ((x >> 16) & 1);   // round-to-nearest-even
    return (unsigned short)(x >> 16);
}

struct __align__(16) U16x8 { unsigned short u[8]; };

// Max across the 16 lanes of a DPP row (laneM) — pure VALU, no LDS pipe.
// dpp_ctrl must be an ICE at the builtin call site -> template parameter.
template <int CTRL>
__device__ __forceinline__ float dppmaxf(float x) {
    int y = __builtin_amdgcn_update_dpp(0, __builtin_bit_cast(int, x),
                                        CTRL, 0xF, 0xF, true);
    return fmaxf(x, __builtin_bit_cast(float, y));
}
__device__ __forceinline__ float rowmax16(float x) {
    x = dppmaxf<0xB1>(x);    // quad_perm [1,0,3,2]  (xor 1)
    x = dppmaxf<0x4E>(x);    // quad_perm [2,3,0,1]  (xor 2)
    x = dppmaxf<0x141>(x);   // row_half_mirror      (xor 4 within 8)
    x = dppmaxf<0x140>(x);   // row_mirror           (xor 8 within 16)
    return x;
}

// Kernel 0: f32 [img][64c][256s] -> bf16 [img][s][c] with chunk XOR swizzle
// (chunk' = (c/8) ^ (s%8)). imgs 0..47 = probe, 48..95 = gallery.
__global__ __launch_bounds__(256) void pretranspose_kernel(
    const float* __restrict__ prob,
    const float* __restrict__ gal,
    unsigned short* __restrict__ outT)   // [96][16384] bf16
{
    const int img = blockIdx.x;
    const float* src = (img < 48) ? (prob + img * 16384)
                                  : (gal + (img - 48) * 16384);
    unsigned short* dst = outT + img * 16384;
    const int tid = threadIdx.x;
    const int c0 = (tid & 7) * 8;
    const int s0 = (tid >> 3) * 8;
    unsigned short v[8][8];
#pragma unroll
    for (int i = 0; i < 8; ++i) {
        const float* p = src + (c0 + i) * 256 + s0;
        const float4v f0 = *(const float4v*)(p);
        const float4v f1 = *(const float4v*)(p + 4);
        v[i][0] = f2bf(f0.x); v[i][1] = f2bf(f0.y);
        v[i][2] = f2bf(f0.z); v[i][3] = f2bf(f0.w);
        v[i][4] = f2bf(f1.x); v[i][5] = f2bf(f1.y);
        v[i][6] = f2bf(f1.z); v[i][7] = f2bf(f1.w);
    }
#pragma unroll
    for (int j = 0; j < 8; ++j) {
        U16x8 o;
#pragma unroll
        for (int i = 0; i < 8; ++i) o.u[i] = v[i][j];
        const int srow = s0 + j;
        const int off = srow * 64 + (((c0 >> 3) ^ (srow & 7)) << 3);
        *(U16x8*)(dst + off) = o;
    }
}

// Kernel A: one block per (probe, gallery) pair. Two mirrored row-max passes:
//   pass 0 (s2): A = gallery rows (global), B = probe (LDS); kept = hr
//   pass 1 (s1): A = probe rows (global),   B = gallery (LDS, restaged); kept = hc
// acc.i = score(row = rt*16 + q*4 + i, col = ct*16 + laneM) in the pass's view.
// dot/sum/sq are additive over rows -> register accumulation, tiny final reduce.
// LDS = 32K + 1K + 256B -> 4 blocks/CU.
__global__ __launch_bounds__(256, 4) void score_pam_kernel(
    const unsigned short* __restrict__ preT,  // [96][16384] bf16 pre-transposed
    const float* __restrict__ fcw,            // [256] f32
    float* __restrict__ outDot,               // [2304]
    float* __restrict__ outSum,               // [2304]
    float* __restrict__ outSq)                // [2304]
{
    __shared__ unsigned short bufB[256 * 64];  // 32 KB: B image [s][c] swizzled
    __shared__ float fcw_lds[256];             // 1 KB
    __shared__ float red[4][4][4];             // 256 B (w, q, {dot,sum,sq,pad})

    const int tid = threadIdx.x;
    const int pair = blockIdx.x;
    const int ip = pair / 48;
    const int ig = pair % 48;
    const unsigned short* pimg = preT + ip * 16384;
    const unsigned short* gimg = preT + (48 + ig) * 16384;

    fcw_lds[tid] = fcw[tid];

    const int lane = tid & 63;
    const int w = tid >> 6;
    const int laneM = lane & 15;
    const int q = lane >> 4;
    const int z = laneM & 7;

    float dot = 0.f, sum = 0.f, sq = 0.f;
    const float msk = (laneM == 0) ? 1.0f : 0.0f;   // count each row once

    int lo[4], hi[4];
#pragma unroll
    for (int j = 0; j < 4; ++j) { lo[j] = LOW[4 * w + j]; hi[j] = HIW[4 * w + j]; }

    for (int pass = 0; pass < 2; ++pass) {
        const unsigned short* Bimg = pass ? gimg : pimg;
        const unsigned short* Aimg = pass ? pimg : gimg;
        if (pass) __syncthreads();     // pass-0 compute done before restage
        // stage B image: linear coalesced 32 KB copy
#pragma unroll
        for (int j = 0; j < 8; ++j) {
            const int off = j * 2048 + tid * 8;
            *(U16x8*)(bufB + off) = *(const U16x8*)(Bimg + off);
        }

        // A-fragments for this wave's 4 row-tiles, straight from global (L2-hot)
        short8 a0[4], a1[4];
#pragma unroll
        for (int j = 0; j < 4; ++j) {
            const int srow = (4 * w + j) * 16 + laneM;
            a0[j] = *(const short8*)(Aimg + srow * 64 + ((q ^ z) << 3));
            a1[j] = *(const short8*)(Aimg + srow * 64 + (((q + 4) ^ z) << 3));
        }

        float4v run[4];
#pragma unroll
        for (int j = 0; j < 4; ++j)
            run[j] = (float4v){ -3.0e38f, -3.0e38f, -3.0e38f, -3.0e38f };

        __syncthreads();               // bufB staged

        // col-tile loop over the union range; B-frags loaded once per ct,
        // shared by all 4 row-tiles (wave-uniform range tests -> scalar branch)
        int sl = lo[0] * 16 + laneM;
        short8 b0 = *(const short8*)(bufB + sl * 64 + ((q ^ z) << 3));
        short8 b1 = *(const short8*)(bufB + sl * 64 + (((q + 4) ^ z) << 3));
        for (int ct = lo[0]; ct <= hi[3]; ++ct) {
            const int ctn = (ct < hi[3]) ? ct + 1 : ct;
            const int sln = ctn * 16 + laneM;
            const short8 nb0 = *(const short8*)(bufB + sln * 64 + ((q ^ z) << 3));
            const short8 nb1 = *(const short8*)(bufB + sln * 64 + (((q + 4) ^ z) << 3));
#pragma unroll
            for (int j = 0; j < 4; ++j) {
                if (ct >= lo[j] && ct <= hi[j]) {
                    float4v acc = { 0.f, 0.f, 0.f, 0.f };
                    acc = __builtin_amdgcn_mfma_f32_16x16x32_bf16(a0[j], b0, acc, 0, 0, 0);
                    acc = __builtin_amdgcn_mfma_f32_16x16x32_bf16(a1[j], b1, acc, 0, 0, 0);
                    run[j].x = fmaxf(run[j].x, acc.x);
                    run[j].y = fmaxf(run[j].y, acc.y);
                    run[j].z = fmaxf(run[j].z, acc.z);
                    run[j].w = fmaxf(run[j].w, acc.w);
                }
            }
            b0 = nb0; b1 = nb1;
        }

        // row-max across the 16 column lanes (DPP, VALU-only), then accumulate
        // this lane's rows into dot/sum/sq (masked to laneM==0 copies).
#pragma unroll
        for (int j = 0; j < 4; ++j) {
            float rx = rowmax16(run[j].x);
            float ry = rowmax16(run[j].y);
            float rz = rowmax16(run[j].z);
            float rw = rowmax16(run[j].w);
            const int rt = 4 * w + j;
            const float4v fw = *(const float4v*)(fcw_lds + rt * 16 + q * 4);
            float t;
            t = msk * rx; dot += t * fw.x; sum += t; sq += t * rx;
            t = msk * ry; dot += t * fw.y; sum += t; sq += t * ry;
            t = msk * rz; dot += t * fw.z; sum += t; sq += t * rz;
            t = msk * rw; dot += t * fw.w; sum += t; sq += t * rw;
        }
    }

    if (laneM == 0) {   // lanes 0,16,32,48 of each wave hold disjoint row sets
        red[w][q][0] = dot; red[w][q][1] = sum; red[w][q][2] = sq;
    }
    __syncthreads();
    if (tid < 3) {
        float s = 0.f;
#pragma unroll
        for (int a = 0; a < 4; ++a)
#pragma unroll
            for (int b = 0; b < 4; ++b) s += red[a][b][tid];
        if (tid == 0) outDot[pair] = s;
        else if (tid == 1) outSum[pair] = s;
        else outSq[pair] = s;
    }
}

// Kernel B: single block. Global BN1 stats from per-pair sums, fc (linear),
// pair-sum, BN2 over 2304, sigmoid, f32 store.
__global__ __launch_bounds__(256) void finalize_kernel(
    const float* __restrict__ dDot,
    const float* __restrict__ dSum,
    const float* __restrict__ dSq,
    const float* __restrict__ bng,
    const float* __restrict__ bnb,
    const float* __restrict__ fcw,
    const float* __restrict__ fcb,
    const float* __restrict__ lg,
    const float* __restrict__ lb,
    float* __restrict__ outp)   // [2304] f32
{
    __shared__ float red[12];
    const int tid = threadIdx.x;
    const int lane = tid & 63;
    const int w = tid >> 6;

    float S = 0.f, Q = 0.f;
    float dv[9];
#pragma unroll
    for (int k = 0; k < 9; ++k) {
        const int i = tid + 256 * k;
        dv[k] = dDot[i];
        S += dSum[i];
        Q += dSq[i];
    }
    float Wj = fcw[tid];
#pragma unroll
    for (int d = 32; d >= 1; d >>= 1) {
        S += __shfl_down(S, d, 64);
        Q += __shfl_down(Q, d, 64);
        Wj += __shfl_down(Wj, d, 64);
    }
    if (lane == 0) { red[w] = S; red[4 + w] = Q; red[8 + w] = Wj; }
    __syncthreads();
    S = red[0] + red[1] + red[2] + red[3];
    Q = red[4] + red[5] + red[6] + red[7];
    const float W = red[8] + red[9] + red[10] + red[11];
    __syncthreads();

    const float N1 = 1179648.0f;           // 4608 * 256 elements in BN1
    const float m1 = S / N1;
    const float v1 = Q / N1 - m1 * m1;     // biased var (torch training default)
    const float inv1 = rsqrtf(v1 + 1e-5f);
    const float g1 = bng[0], b1 = bnb[0], fb = fcb[0];
    const float g2 = lg[0], b2 = lb[0];
    const float cA = g1 * inv1;
    const float cB = 2.f * (b1 * W + fb) - cA * 2.f * m1 * W;

    float Sy = 0.f, Qy = 0.f;
    float yv[9];
#pragma unroll
    for (int k = 0; k < 9; ++k) {
        const float y = cA * dv[k] + cB;
        yv[k] = y;
        Sy += y;
        Qy += y * y;
    }
#pragma unroll
    for (int d = 32; d >= 1; d >>= 1) {
        Sy += __shfl_down(Sy, d, 64);
        Qy += __shfl_down(Qy, d, 64);
    }
    if (lane == 0) { red[w] = Sy; red[4 + w] = Qy; }
    __syncthreads();
    Sy = red[0] + red[1] + red[2] + red[3];
    Qy = red[4] + red[5] + red[6] + red[7];

    const float m2 = Sy / 2304.0f;
    const float v2 = Qy / 2304.0f - m2 * m2;
    const float inv2 = rsqrtf(v2 + 1e-5f);
#pragma unroll
    for (int k = 0; k < 9; ++k) {
        const int i = tid + 256 * k;
        const float z = g2 * (yv[k] - m2) * inv2 + b2;
        outp[i] = 1.0f / (1.0f + __expf(-z));
    }
}

extern "C" void kernel_launch(void* const* d_in, const int* in_sizes, int n_in,
                              void* d_out, int out_size, void* d_ws, size_t ws_size,
                              hipStream_t stream) {
    const float* prob = (const float*)d_in[0];
    const float* gal  = (const float*)d_in[1];
    const float* bng  = (const float*)d_in[2];
    const float* bnb  = (const float*)d_in[3];
    const float* fcw  = (const float*)d_in[4];
    const float* fcb  = (const float*)d_in[5];
    const float* lg   = (const float*)d_in[6];
    const float* lb   = (const float*)d_in[7];

    unsigned short* preT = (unsigned short*)d_ws;        // 96*16384 bf16 = 3 MB
    float* ws = (float*)((char*)d_ws + 96 * 16384 * sizeof(unsigned short));
    float* dDot = ws;            // [2304]
    float* dSum = ws + 2304;     // [2304]
    float* dSq  = ws + 4608;     // [2304]

    hipLaunchKernelGGL(pretranspose_kernel, dim3(96), dim3(256), 0, stream,
                       prob, gal, preT);
    hipLaunchKernelGGL(score_pam_kernel, dim3(48 * 48), dim3(256), 0, stream,
                       preT, fcw, dDot, dSum, dSq);
    hipLaunchKernelGGL(finalize_kernel, dim3(1), dim3(256), 0, stream,
                       dDot, dSum, dSq, bng, bnb, fcw, fcb, lg, lb,
                       (float*)d_out);
}